// Round 10
// baseline (132.166 us; speedup 1.0000x reference)
//
#include <hip/hip_runtime.h>
#include <cstdint>
#include <cstddef>

// MMD loss, N=8192 (b=4096), D=512.
//   R11: ONE-SHOT PANEL STAGING k_mmd + tiny k_bw.
//        Budget: 45us harness fill (fixed) + kernels. k_mmd theory: R6
//        (no-LDS) == R7 (dbuf-LDS) == ~43-48us because BOTH pay a global
//        latency (~600-900cyc; Ti8=4MB == one XCD L2, spills to L3) on
//        EVERY of 8 K-steps at ~1 resident block/CU. Fix: frag-major makes
//        a tile's panel CONTIGUOUS 64KB -> stage A+B fully into 128KB LDS
//        (one barrier), then 8 K-steps of pure ds_read+MFMA, zero barriers,
//        zero global deps. One latency wait per block instead of 9.
//        Pred: k_mmd 48->13-20us; if >=40, latency theory falsified ->
//        epilogue next. k_bw: R9's 1MB single-block read (~16us) -> 16KB
//        super-partials via int atomicAdd in k_rowstats (exact), memset-
//        zeroed. Pred k_bw <=2us. Total pred ~78-88us.
//   R9: hierarchical fence-free ticket (64 line-spread counters -> 1 L2);
//       k_rowstats: per-rb block, LDS-transposed coalesced frag-major out.
//   R7: global_load_lds width=16; XCD swizzle (2080=8*260, bijective).
//   R6: FRAGMENT-MAJOR int8: chunk (rb,c) [16rows x 16B] = 256B contiguous;
//       tile panel (8 rb) = contiguous 64KB (enables R11 one-shot).
//   R4: INT8 MFMA 16x16x64 (scale 1/16, exact i32 acc), diag forced exact.
//   Epilogue: sum_k exp(-L2/(bw*2^k)) = e+e^2+e^4+e^8+e^16.

#define D_DIM 512
#define B_ROWS 4096
#define N_ROWS 8192
#define NTILES 64        // 8192 / 128
#define NBLK_MMD 2080    // 64*65/2
#define QPITCH 528       // rowstats LDS row pitch (512 + 16 pad)

typedef __attribute__((ext_vector_type(4))) int i32x4;

__device__ inline float waveReduce(float v) {
    #pragma unroll
    for (int off = 32; off > 0; off >>= 1) v += __shfl_down(v, off, 64);
    return v;
}

__device__ inline int q8(float x) {
    int v = (int)rintf(x * 16.f);             // RNE; s = 1/16
    v = v > 127 ? 127 : v;
    v = v < -127 ? -127 : v;
    return v & 255;
}

// ---- K1: sq norms + int8 quantize (coalesced frag-major via LDS) +
//          colsum -> 8 line-spread super-partials (int atomics, exact). ----
__global__ __launch_bounds__(256) void k_rowstats(const float* __restrict__ src,
                                                  const float* __restrict__ tgt,
                                                  unsigned char* __restrict__ Tp,
                                                  float* __restrict__ sq,
                                                  int* __restrict__ sp,
                                                  unsigned int* __restrict__ tk) {
    if (blockIdx.x == 0 && threadIdx.x < 65)
        tk[threadIdx.x * 16] = 0u;           // ticket counters (replay-safe)

    __shared__ unsigned char Q[16 * QPITCH]; // 8448 B
    int tid = threadIdx.x, wave = tid >> 6, lane = tid & 63;
    int rb = blockIdx.x;                     // 0..511

    #pragma unroll
    for (int i = 0; i < 4; ++i) {
        int rl  = wave * 4 + i;
        int row = rb * 16 + rl;
        const float* base = (row < B_ROWS) ? (src + (size_t)row * D_DIM)
                                           : (tgt + (size_t)(row - B_ROWS) * D_DIM);
        float4 a = ((const float4*)base)[lane * 2];
        float4 b = ((const float4*)base)[lane * 2 + 1];
        uint2 o;  // bytes [8*lane, 8*lane+8) of the quantized row
        o.x = (unsigned)(q8(a.x) | (q8(a.y) << 8) | (q8(a.z) << 16) | (q8(a.w) << 24));
        o.y = (unsigned)(q8(b.x) | (q8(b.y) << 8) | (q8(b.z) << 16) | (q8(b.w) << 24));
        *(uint2*)(Q + rl * QPITCH + lane * 8) = o;   // 2-way bank alias: free
        float s = a.x*a.x + a.y*a.y + a.z*a.z + a.w*a.w
                + b.x*b.x + b.y*b.y + b.z*b.z + b.w*b.w;
        s = waveReduce(s);
        if (lane == 0) sq[row] = s;
    }
    __syncthreads();

    // per-rb column sums (2 cols/thread) -> atomicAdd into group rb&7.
    // int adds are associative -> bitwise-deterministic across replays.
    int s0 = 0, s1 = 0;
    #pragma unroll
    for (int r = 0; r < 16; ++r) {
        unsigned short v = *(const unsigned short*)(Q + r * QPITCH + tid * 2);
        s0 += (int)(signed char)(v & 255);
        s1 += (int)(signed char)(v >> 8);
    }
    int gbase = (rb & 7) * 512 + tid * 2;
    atomicAdd(&sp[gbase],     s0);
    atomicAdd(&sp[gbase + 1], s1);

    // frag-major writeout: thread t -> chunk c = t>>3, rows idx*2, idx*2+1.
    int c = tid >> 3, idx = tid & 7;
    uint4 lo = *(const uint4*)(Q + (idx * 2)     * QPITCH + c * 16);
    uint4 hi = *(const uint4*)(Q + (idx * 2 + 1) * QPITCH + c * 16);
    unsigned char* gout = Tp + ((size_t)rb << 13) + c * 256 + idx * 32;
    *(uint4*)(gout)      = lo;
    *(uint4*)(gout + 16) = hi;
}

// ---- K2: finalize bandwidth -> c16 = -log2(e)/(16*bw) (1 block, 16KB in) ----
__global__ __launch_bounds__(512) void k_bw(const int* __restrict__ sp,
                                            const float* __restrict__ sq,
                                            float* __restrict__ c16out) {
    int t = threadIdx.x;
    int csum = 0;
    #pragma unroll
    for (int g = 0; g < 8; ++g) csum += sp[g * 512 + t];   // coalesced, 16KB
    float cs = (float)csum * 0.0625f;          // * s (1/16)
    float p = cs * cs;
    float ssq = 0.f;
    #pragma unroll
    for (int i = 0; i < 16; ++i) ssq += sq[t + i * 512];
    __shared__ float r8[8], q8s[8];
    float wp = waveReduce(p);
    float wq = waveReduce(ssq);
    if ((t & 63) == 0) { r8[t >> 6] = wp; q8s[t >> 6] = wq; }
    __syncthreads();
    if (t == 0) {
        double P = 0.0, Q = 0.0;
        #pragma unroll
        for (int i = 0; i < 8; ++i) { P += r8[i]; Q += q8s[i]; }
        double n = (double)N_ROWS;
        double sumL2 = 2.0 * n * Q - 2.0 * P;
        double bw = sumL2 / (n * n - n) / 4.0;   // / KERNEL_MUL^(NUM/2)
        c16out[0] = (float)(-1.4426950408889634 / (16.0 * bw));
    }
}

// ---- K3: one-shot-staged int8 Gram + fused MMD epilogue + hier. ticket ----
__global__ __launch_bounds__(256) void k_mmd(const unsigned char* __restrict__ Tp,
                                             const float* __restrict__ sq,
                                             const float* __restrict__ c16in,
                                             float* __restrict__ blockpart,
                                             float* __restrict__ out,
                                             unsigned int* __restrict__ tk) {
    int hwbid = (int)blockIdx.x;
    int bid = (hwbid & 7) * 260 + (hwbid >> 3);   // XCD swizzle (bijective)

    int rem = bid;
    int ti = 0, rowlen = NTILES;
    while (rem >= rowlen) { rem -= rowlen; rowlen--; ti++; }
    int tj = ti + rem;

    int tid  = threadIdx.x;
    int wave = tid >> 6;
    int lane = tid & 63;
    int waveM = (wave >> 1) * 64;
    int waveN = (wave & 1) * 64;
    int l15   = lane & 15;
    int quad  = lane >> 4;

    float c16 = c16in[0];                    // -log2e/(16 bw)
    float cgq = -2.f * c16 * (1.f / 256.f);  // fold s^2 = 1/256

    // One-shot stage: tile panels are CONTIGUOUS 64KB in frag-major layout.
    __shared__ unsigned char lds[131072];    // A: [0,64K)  B: [64K,128K)
    unsigned char* ldsA = lds;
    unsigned char* ldsB = lds + 65536;
    const unsigned char* gA = Tp + ((size_t)ti << 16);
    const unsigned char* gB = Tp + ((size_t)tj << 16);
    #pragma unroll
    for (int i = 0; i < 16; ++i) {
        int o = (i * 256 + tid) * 16;        // lanes linear: valid lds dest
        __builtin_amdgcn_global_load_lds(
            (const __attribute__((address_space(1))) void*)(gA + o),
            (__attribute__((address_space(3))) void*)(ldsA + o), 16, 0, 0);
        __builtin_amdgcn_global_load_lds(
            (const __attribute__((address_space(1))) void*)(gB + o),
            (__attribute__((address_space(3))) void*)(ldsB + o), 16, 0, 0);
    }
    __syncthreads();                         // the ONLY global-latency wait

    i32x4 acc[4][4];
    #pragma unroll
    for (int mi = 0; mi < 4; ++mi)
        #pragma unroll
        for (int ni = 0; ni < 4; ++ni)
            acc[mi][ni] = (i32x4){0, 0, 0, 0};

    int arow = (wave >> 1) * 4;              // rb_local base of A rows
    int brow = (wave & 1) * 4;
    // 8 K-steps, straight-line, ZERO barriers, ZERO global deps:
    // compiler pipelines ds_reads of kk+1 under MFMAs of kk.
    #pragma unroll
    for (int kk = 0; kk < 8; ++kk) {
        int coff = (kk * 4 + quad) * 256 + l15 * 16;
        i32x4 af[4], bf[4];
        #pragma unroll
        for (int mi = 0; mi < 4; ++mi)
            af[mi] = *(const i32x4*)(ldsA + (arow + mi) * 8192 + coff);
        #pragma unroll
        for (int ni = 0; ni < 4; ++ni)
            bf[ni] = *(const i32x4*)(ldsB + (brow + ni) * 8192 + coff);
        #pragma unroll
        for (int mi = 0; mi < 4; ++mi)
            #pragma unroll
            for (int ni = 0; ni < 4; ++ni)
                acc[mi][ni] = __builtin_amdgcn_mfma_i32_16x16x64_i8(
                    af[mi], bf[ni], acc[mi][ni], 0, 0, 0);
    }

    const float* sqA = sq + ti * 128;
    const float* sqB = sq + tj * 128;
    float trow16[16];
    #pragma unroll
    for (int mi = 0; mi < 4; ++mi)
        #pragma unroll
        for (int r = 0; r < 4; ++r)
            trow16[mi * 4 + r] = sqA[waveM + mi * 16 + quad * 4 + r] * c16;
    float tcol16[4];
    #pragma unroll
    for (int ni = 0; ni < 4; ++ni)
        tcol16[ni] = sqB[waveN + ni * 16 + l15] * c16;

    float psum = 0.f;
    if (ti != tj) {
        // off-diagonal: no per-element diagonal check (2016/2080 blocks)
        #pragma unroll
        for (int mi = 0; mi < 4; ++mi) {
            #pragma unroll
            for (int ni = 0; ni < 4; ++ni) {
                #pragma unroll
                for (int r = 0; r < 4; ++r) {
                    float g   = (float)acc[mi][ni][r];   // exact: |G| < 2^24
                    float t16 = __builtin_fmaf(g, cgq, trow16[mi * 4 + r]) + tcol16[ni];
                    float e1  = __builtin_amdgcn_exp2f(t16);
                    float e2  = e1 * e1;
                    float e4  = e2 * e2;
                    float e8  = e4 * e4;
                    float e16 = e8 * e8;
                    psum += ((e1 + e2) + (e4 + e8)) + e16;
                }
            }
        }
    } else {
        #pragma unroll
        for (int mi = 0; mi < 4; ++mi) {
            #pragma unroll
            for (int ni = 0; ni < 4; ++ni) {
                #pragma unroll
                for (int r = 0; r < 4; ++r) {
                    float g   = (float)acc[mi][ni][r];
                    float t16 = __builtin_fmaf(g, cgq, trow16[mi * 4 + r]) + tcol16[ni];
                    float e1  = __builtin_amdgcn_exp2f(t16);
                    float e2  = e1 * e1;
                    float e4  = e2 * e2;
                    float e8  = e4 * e4;
                    float e16 = e8 * e8;
                    float ks5 = ((e1 + e2) + (e4 + e8)) + e16;
                    int rl = waveM + mi * 16 + quad * 4 + r;
                    int cl = waveN + ni * 16 + l15;
                    psum += (rl == cl) ? 5.0f : ks5;     // exact diagonal
                }
            }
        }
    }

    // Reduction scratch aliases lds[0..16); barrier first so no wave still
    // reads staged data (race-free by sync, not by timing).
    __syncthreads();
    float* red   = (float*)lds;              // bytes 0..15
    int*   flagp = (int*)lds + 4;            // bytes 16..19
    float w = waveReduce(psum);
    if (lane == 0) red[wave] = w;
    __syncthreads();
    if (tid == 0) {
        float tot   = red[0] + red[1] + red[2] + red[3];
        float sign  = ((ti < 32) == (tj < 32)) ? 1.f : -1.f;
        float scale = (ti == tj) ? sign : 2.f * sign;
        __hip_atomic_store(&blockpart[hwbid], tot * scale,
                           __ATOMIC_RELAXED, __HIP_MEMORY_SCOPE_AGENT);
        asm volatile("s_waitcnt vmcnt(0)" ::: "memory");  // store < ticket
        unsigned g = (unsigned)hwbid & 63u;
        unsigned tgt = (g < 32u) ? 33u : 32u;             // 2080 = 32*33+32*32
        unsigned prev = __hip_atomic_fetch_add(&tk[g * 16], 1u,
                            __ATOMIC_RELAXED, __HIP_MEMORY_SCOPE_AGENT);
        int last = 0;
        if (prev == tgt - 1u)
            last = (__hip_atomic_fetch_add(&tk[64 * 16], 1u,
                        __ATOMIC_RELAXED, __HIP_MEMORY_SCOPE_AGENT) == 63u);
        *flagp = last;
    }
    __syncthreads();
    if (!*flagp) return;

    // winner: every blockpart store precedes its ticket RMW; all RMWs
    // precede ours -> agent-scope loads observe all 2080 values.
    float s = 0.f;
    for (int i = tid; i < NBLK_MMD; i += 256)
        s += __hip_atomic_load(&blockpart[i], __ATOMIC_RELAXED,
                               __HIP_MEMORY_SCOPE_AGENT);
    float ws = waveReduce(s);
    __syncthreads();
    if (lane == 0) red[wave] = ws;
    __syncthreads();
    if (tid == 0)
        out[0] = (red[0] + red[1] + red[2] + red[3]) * (1.f / (4096.f * 4096.f));
}

extern "C" void kernel_launch(void* const* d_in, const int* in_sizes, int n_in,
                              void* d_out, int out_size, void* d_ws, size_t ws_size,
                              hipStream_t stream) {
    const float* src = (const float*)d_in[0];
    const float* tgt = (const float*)d_in[1];

    uint8_t* ws = (uint8_t*)d_ws;
    unsigned char* Tp = (unsigned char*)ws;                     // 4,194,304 B
    size_t off = 4194304;
    float* sq      = (float*)(ws + off); off += 32768;          // 8192 f
    int*   sp      = (int*)  (ws + off); off += 16384;          // 8x512 i32
    float* bp      = (float*)(ws + off); off += 8320;
    float* c16     = (float*)(ws + off); off += 64;
    unsigned int* tk = (unsigned int*)(ws + off);               // 65*16 uints

    hipMemsetAsync(sp, 0, 16384, stream);   // zero super-partials (capturable)
    k_rowstats<<<512, 256, 0, stream>>>(src, tgt, Tp, sq, sp, tk);
    k_bw      <<<1, 512, 0, stream>>>(sp, sq, c16);
    k_mmd     <<<NBLK_MMD, 256, 0, stream>>>(Tp, sq, c16, bp, (float*)d_out, tk);
}

// Round 12
// 112.844 us; speedup vs baseline: 1.1712x; 1.1712x over previous
//
#include <hip/hip_runtime.h>
#include <cstdint>
#include <cstddef>

// MMD loss, N=8192 (b=4096), D=512.
//   R12: A-IN-LDS + B-DIRECT, ZERO-BARRIER K-LOOP.
//        R11 post-mortem: one-shot 128KB LDS -> 1 block/CU (8.4% occ) ->
//        65us. Cross-round: VALU-busy (16us) and MFMA-busy (6.5us) are
//        CONSTANT across R9/R11 -- all variance is stall time, set by how
//        much resident work overlaps staging latency. Fix both axes:
//        A panel (contiguous 64KB frag-major) one-shot into 64KB LDS ->
//        2 blocks/CU; B fragments read per-wave DIRECT from global (R6
//        proved path parity), so the unrolled K-loop has ZERO barriers --
//        no vmcnt(0)+s_barrier drain, compiler free to pipeline B-loads
//        of kk+1 under MFMAs of kk. L3 traffic unchanged (64+64KB/block;
//        wave-pair B reuse hits L1). Pred: serialization-bound -> k_mmd
//        22-30us (total ~90-100); L3-BW-bound -> pinned ~44 (total ~110)
//        and next lever = 256^2 tiles.
//   R11: one-shot staging (REGRESSED, reverted); tiny k_bw via
//        super-partials (KEPT: k_bw ~16us -> ~2us).
//   R9: hierarchical fence-free ticket (64 line-spread counters -> 1 L2);
//       k_rowstats: per-rb block, LDS-transposed coalesced frag-major out.
//   R6/R7: FRAGMENT-MAJOR int8: chunk (rb,c) [16rows x 16B] = 256B; panel
//        (8rb) = contiguous 64KB. XCD swizzle (2080=8*260, bijective).
//   R4: INT8 MFMA 16x16x64 (scale 1/16, exact i32 acc), diag forced exact.
//   Epilogue: sum_k exp(-L2/(bw*2^k)) = e+e^2+e^4+e^8+e^16.

#define D_DIM 512
#define B_ROWS 4096
#define N_ROWS 8192
#define NTILES 64        // 8192 / 128
#define NBLK_MMD 2080    // 64*65/2
#define QPITCH 528       // rowstats LDS row pitch (512 + 16 pad)

typedef __attribute__((ext_vector_type(4))) int i32x4;

__device__ inline float waveReduce(float v) {
    #pragma unroll
    for (int off = 32; off > 0; off >>= 1) v += __shfl_down(v, off, 64);
    return v;
}

__device__ inline int q8(float x) {
    int v = (int)rintf(x * 16.f);             // RNE; s = 1/16
    v = v > 127 ? 127 : v;
    v = v < -127 ? -127 : v;
    return v & 255;
}

// ---- K1: sq norms + int8 quantize (coalesced frag-major via LDS) +
//          colsum -> 8 line-spread super-partials (int atomics, exact). ----
__global__ __launch_bounds__(256) void k_rowstats(const float* __restrict__ src,
                                                  const float* __restrict__ tgt,
                                                  unsigned char* __restrict__ Tp,
                                                  float* __restrict__ sq,
                                                  int* __restrict__ sp,
                                                  unsigned int* __restrict__ tk) {
    if (blockIdx.x == 0 && threadIdx.x < 65)
        tk[threadIdx.x * 16] = 0u;           // ticket counters (replay-safe)

    __shared__ unsigned char Q[16 * QPITCH]; // 8448 B
    int tid = threadIdx.x, wave = tid >> 6, lane = tid & 63;
    int rb = blockIdx.x;                     // 0..511

    #pragma unroll
    for (int i = 0; i < 4; ++i) {
        int rl  = wave * 4 + i;
        int row = rb * 16 + rl;
        const float* base = (row < B_ROWS) ? (src + (size_t)row * D_DIM)
                                           : (tgt + (size_t)(row - B_ROWS) * D_DIM);
        float4 a = ((const float4*)base)[lane * 2];
        float4 b = ((const float4*)base)[lane * 2 + 1];
        uint2 o;  // bytes [8*lane, 8*lane+8) of the quantized row
        o.x = (unsigned)(q8(a.x) | (q8(a.y) << 8) | (q8(a.z) << 16) | (q8(a.w) << 24));
        o.y = (unsigned)(q8(b.x) | (q8(b.y) << 8) | (q8(b.z) << 16) | (q8(b.w) << 24));
        *(uint2*)(Q + rl * QPITCH + lane * 8) = o;   // 2-way bank alias: free
        float s = a.x*a.x + a.y*a.y + a.z*a.z + a.w*a.w
                + b.x*b.x + b.y*b.y + b.z*b.z + b.w*b.w;
        s = waveReduce(s);
        if (lane == 0) sq[row] = s;
    }
    __syncthreads();

    // per-rb column sums (2 cols/thread) -> atomicAdd into group rb&7.
    int s0 = 0, s1 = 0;
    #pragma unroll
    for (int r = 0; r < 16; ++r) {
        unsigned short v = *(const unsigned short*)(Q + r * QPITCH + tid * 2);
        s0 += (int)(signed char)(v & 255);
        s1 += (int)(signed char)(v >> 8);
    }
    int gbase = (rb & 7) * 512 + tid * 2;
    atomicAdd(&sp[gbase],     s0);
    atomicAdd(&sp[gbase + 1], s1);

    // frag-major writeout: thread t -> chunk c = t>>3, rows idx*2, idx*2+1.
    int c = tid >> 3, idx = tid & 7;
    uint4 lo = *(const uint4*)(Q + (idx * 2)     * QPITCH + c * 16);
    uint4 hi = *(const uint4*)(Q + (idx * 2 + 1) * QPITCH + c * 16);
    unsigned char* gout = Tp + ((size_t)rb << 13) + c * 256 + idx * 32;
    *(uint4*)(gout)      = lo;
    *(uint4*)(gout + 16) = hi;
}

// ---- K2: finalize bandwidth -> c16 = -log2(e)/(16*bw) (1 block, 16KB in) ----
__global__ __launch_bounds__(512) void k_bw(const int* __restrict__ sp,
                                            const float* __restrict__ sq,
                                            float* __restrict__ c16out) {
    int t = threadIdx.x;
    int csum = 0;
    #pragma unroll
    for (int g = 0; g < 8; ++g) csum += sp[g * 512 + t];   // coalesced, 16KB
    float cs = (float)csum * 0.0625f;          // * s (1/16)
    float p = cs * cs;
    float ssq = 0.f;
    #pragma unroll
    for (int i = 0; i < 16; ++i) ssq += sq[t + i * 512];
    __shared__ float r8[8], q8s[8];
    float wp = waveReduce(p);
    float wq = waveReduce(ssq);
    if ((t & 63) == 0) { r8[t >> 6] = wp; q8s[t >> 6] = wq; }
    __syncthreads();
    if (t == 0) {
        double P = 0.0, Q = 0.0;
        #pragma unroll
        for (int i = 0; i < 8; ++i) { P += r8[i]; Q += q8s[i]; }
        double n = (double)N_ROWS;
        double sumL2 = 2.0 * n * Q - 2.0 * P;
        double bw = sumL2 / (n * n - n) / 4.0;   // / KERNEL_MUL^(NUM/2)
        c16out[0] = (float)(-1.4426950408889634 / (16.0 * bw));
    }
}

// ---- K3: A-in-LDS + B-direct int8 Gram, zero-barrier K-loop,
//          fused MMD epilogue + hierarchical ticket ----
__global__ __launch_bounds__(256) void k_mmd(const unsigned char* __restrict__ Tp,
                                             const float* __restrict__ sq,
                                             const float* __restrict__ c16in,
                                             float* __restrict__ blockpart,
                                             float* __restrict__ out,
                                             unsigned int* __restrict__ tk) {
    int hwbid = (int)blockIdx.x;
    int bid = (hwbid & 7) * 260 + (hwbid >> 3);   // XCD swizzle (bijective)

    int rem = bid;
    int ti = 0, rowlen = NTILES;
    while (rem >= rowlen) { rem -= rowlen; rowlen--; ti++; }
    int tj = ti + rem;

    int tid  = threadIdx.x;
    int wave = tid >> 6;
    int lane = tid & 63;
    int waveM = (wave >> 1) * 64;
    int waveN = (wave & 1) * 64;
    int l15   = lane & 15;
    int quad  = lane >> 4;

    float c16 = c16in[0];                    // -log2e/(16 bw)
    float cgq = -2.f * c16 * (1.f / 256.f);  // fold s^2 = 1/256

    // One-shot stage of the A panel only (contiguous 64KB, frag-major).
    __shared__ unsigned char ldsA[65536];    // 64KB -> 2 blocks/CU
    const unsigned char* gA = Tp + ((size_t)ti << 16);
    const unsigned char* gB = Tp + ((size_t)tj << 16);
    #pragma unroll
    for (int i = 0; i < 16; ++i) {
        int o = (i * 256 + tid) * 16;        // lanes linear: valid lds dest
        __builtin_amdgcn_global_load_lds(
            (const __attribute__((address_space(1))) void*)(gA + o),
            (__attribute__((address_space(3))) void*)(ldsA + o), 16, 0, 0);
    }
    __syncthreads();                         // the ONLY barrier before epilogue

    i32x4 acc[4][4];
    #pragma unroll
    for (int mi = 0; mi < 4; ++mi)
        #pragma unroll
        for (int ni = 0; ni < 4; ++ni)
            acc[mi][ni] = (i32x4){0, 0, 0, 0};

    int arow = (wave >> 1) * 4;              // rb_local base of A rows
    int brow = (wave & 1) * 4;
    // 8 K-steps, fully unrolled, ZERO barriers: B loads are wave-private
    // globals -> compiler pipelines kk+1 loads under kk MFMAs. Wave pairs
    // (0,2)/(1,3) read identical B lines back-to-back -> L1 hits; L3
    // traffic stays 64KB(A)+64KB(B) per block.
    #pragma unroll
    for (int kk = 0; kk < 8; ++kk) {
        int coff = (kk * 4 + quad) * 256 + l15 * 16;
        i32x4 af[4], bf[4];
        #pragma unroll
        for (int ni = 0; ni < 4; ++ni)
            bf[ni] = *(const i32x4*)(gB + (size_t)((brow + ni) * 8192 + coff));
        #pragma unroll
        for (int mi = 0; mi < 4; ++mi)
            af[mi] = *(const i32x4*)(ldsA + (arow + mi) * 8192 + coff);
        #pragma unroll
        for (int mi = 0; mi < 4; ++mi)
            #pragma unroll
            for (int ni = 0; ni < 4; ++ni)
                acc[mi][ni] = __builtin_amdgcn_mfma_i32_16x16x64_i8(
                    af[mi], bf[ni], acc[mi][ni], 0, 0, 0);
    }

    const float* sqA = sq + ti * 128;
    const float* sqB = sq + tj * 128;
    float trow16[16];
    #pragma unroll
    for (int mi = 0; mi < 4; ++mi)
        #pragma unroll
        for (int r = 0; r < 4; ++r)
            trow16[mi * 4 + r] = sqA[waveM + mi * 16 + quad * 4 + r] * c16;
    float tcol16[4];
    #pragma unroll
    for (int ni = 0; ni < 4; ++ni)
        tcol16[ni] = sqB[waveN + ni * 16 + l15] * c16;

    float psum = 0.f;
    if (ti != tj) {
        // off-diagonal: no per-element diagonal check (2016/2080 blocks)
        #pragma unroll
        for (int mi = 0; mi < 4; ++mi) {
            #pragma unroll
            for (int ni = 0; ni < 4; ++ni) {
                #pragma unroll
                for (int r = 0; r < 4; ++r) {
                    float g   = (float)acc[mi][ni][r];   // exact: |G| < 2^24
                    float t16 = __builtin_fmaf(g, cgq, trow16[mi * 4 + r]) + tcol16[ni];
                    float e1  = __builtin_amdgcn_exp2f(t16);
                    float e2  = e1 * e1;
                    float e4  = e2 * e2;
                    float e8  = e4 * e4;
                    float e16 = e8 * e8;
                    psum += ((e1 + e2) + (e4 + e8)) + e16;
                }
            }
        }
    } else {
        #pragma unroll
        for (int mi = 0; mi < 4; ++mi) {
            #pragma unroll
            for (int ni = 0; ni < 4; ++ni) {
                #pragma unroll
                for (int r = 0; r < 4; ++r) {
                    float g   = (float)acc[mi][ni][r];
                    float t16 = __builtin_fmaf(g, cgq, trow16[mi * 4 + r]) + tcol16[ni];
                    float e1  = __builtin_amdgcn_exp2f(t16);
                    float e2  = e1 * e1;
                    float e4  = e2 * e2;
                    float e8  = e4 * e4;
                    float e16 = e8 * e8;
                    float ks5 = ((e1 + e2) + (e4 + e8)) + e16;
                    int rl = waveM + mi * 16 + quad * 4 + r;
                    int cl = waveN + ni * 16 + l15;
                    psum += (rl == cl) ? 5.0f : ks5;     // exact diagonal
                }
            }
        }
    }

    // Reduction scratch aliases ldsA[0..20); barrier first so no wave still
    // reads staged data.
    __syncthreads();
    float* red   = (float*)ldsA;             // bytes 0..15
    int*   flagp = (int*)ldsA + 4;           // bytes 16..19
    float w = waveReduce(psum);
    if (lane == 0) red[wave] = w;
    __syncthreads();
    if (tid == 0) {
        float tot   = red[0] + red[1] + red[2] + red[3];
        float sign  = ((ti < 32) == (tj < 32)) ? 1.f : -1.f;
        float scale = (ti == tj) ? sign : 2.f * sign;
        __hip_atomic_store(&blockpart[hwbid], tot * scale,
                           __ATOMIC_RELAXED, __HIP_MEMORY_SCOPE_AGENT);
        asm volatile("s_waitcnt vmcnt(0)" ::: "memory");  // store < ticket
        unsigned g = (unsigned)hwbid & 63u;
        unsigned tgt = (g < 32u) ? 33u : 32u;             // 2080 = 32*33+32*32
        unsigned prev = __hip_atomic_fetch_add(&tk[g * 16], 1u,
                            __ATOMIC_RELAXED, __HIP_MEMORY_SCOPE_AGENT);
        int last = 0;
        if (prev == tgt - 1u)
            last = (__hip_atomic_fetch_add(&tk[64 * 16], 1u,
                        __ATOMIC_RELAXED, __HIP_MEMORY_SCOPE_AGENT) == 63u);
        *flagp = last;
    }
    __syncthreads();
    if (!*flagp) return;

    // winner: every blockpart store precedes its ticket RMW; all RMWs
    // precede ours -> agent-scope loads observe all 2080 values.
    float s = 0.f;
    for (int i = tid; i < NBLK_MMD; i += 256)
        s += __hip_atomic_load(&blockpart[i], __ATOMIC_RELAXED,
                               __HIP_MEMORY_SCOPE_AGENT);
    float ws = waveReduce(s);
    __syncthreads();
    if (lane == 0) red[wave] = ws;
    __syncthreads();
    if (tid == 0)
        out[0] = (red[0] + red[1] + red[2] + red[3]) * (1.f / (4096.f * 4096.f));
}

extern "C" void kernel_launch(void* const* d_in, const int* in_sizes, int n_in,
                              void* d_out, int out_size, void* d_ws, size_t ws_size,
                              hipStream_t stream) {
    const float* src = (const float*)d_in[0];
    const float* tgt = (const float*)d_in[1];

    uint8_t* ws = (uint8_t*)d_ws;
    unsigned char* Tp = (unsigned char*)ws;                     // 4,194,304 B
    size_t off = 4194304;
    float* sq      = (float*)(ws + off); off += 32768;          // 8192 f
    int*   sp      = (int*)  (ws + off); off += 16384;          // 8x512 i32
    float* bp      = (float*)(ws + off); off += 8320;
    float* c16     = (float*)(ws + off); off += 64;
    unsigned int* tk = (unsigned int*)(ws + off);               // 65*16 uints

    hipMemsetAsync(sp, 0, 16384, stream);   // zero super-partials (capturable)
    k_rowstats<<<512, 256, 0, stream>>>(src, tgt, Tp, sq, sp, tk);
    k_bw      <<<1, 512, 0, stream>>>(sp, sq, c16);
    k_mmd     <<<NBLK_MMD, 256, 0, stream>>>(Tp, sq, c16, bp, (float*)d_out, tk);
}